// Round 1
// baseline (431.926 us; speedup 1.0000x reference)
//
#include <hip/hip_runtime.h>
#include <hip/hip_bf16.h>

typedef unsigned short u16;
typedef __bf16 bf16x8 __attribute__((ext_vector_type(8)));
typedef float f32x4 __attribute__((ext_vector_type(4)));

#define NROWS 32768
#define H 512
#define NS 8
#define NR 64
#define NT 12

// workspace layout (bytes)
#define WS_W1T   0            // [8][512][512] bf16 = 4194304
#define WS_UCT   4194304      // [512][512] bf16    = 524288
#define WS_W2T   4718592      // [8][16][512] bf16  = 131072
#define WS_CVEC  4849664      // [8][64] f32        = 2048

union BFU { __bf16 h; u16 u; };
__device__ __forceinline__ u16 f2bf(float v) { BFU b; b.h = (__bf16)v; return b.u; }

// ---------- prep: batched transpose + cast to bf16, out[b][c][r] = in[b][r][c] (c<Cc else 0) ----------
__global__ __launch_bounds__(256) void transpose_cast(const float* __restrict__ in,
    u16* __restrict__ out, int Rr, int Cc, int Cpad) {
  __shared__ float tile[32][33];
  int b = blockIdx.z, r0 = blockIdx.x * 32, c0 = blockIdx.y * 32;
  int tx = threadIdx.x, ty = threadIdx.y;
#pragma unroll
  for (int i = 0; i < 4; i++) {
    int r = r0 + ty + i * 8, c = c0 + tx;
    float v = 0.f;
    if (r < Rr && c < Cc) v = in[((size_t)b * Rr + r) * Cc + c];
    tile[ty + i * 8][tx] = v;
  }
  __syncthreads();
#pragma unroll
  for (int i = 0; i < 4; i++) {
    int c = c0 + ty + i * 8, r = r0 + tx;
    if (c < Cpad && r < Rr) out[((size_t)b * Cpad + c) * Rr + r] = f2bf(tile[tx][ty + i * 8]);
  }
}

// ---------- prep: c[s][r] = sum_k mu[s][k] * Us[s][k][r] ----------
__global__ void compute_c(const float* __restrict__ mu, const float* __restrict__ Us,
                          float* __restrict__ cvec) {
  int t = threadIdx.x, s = t >> 6, r = t & 63;
  float acc = 0.f;
  for (int k = 0; k < H; k++) acc += mu[s * H + k] * Us[((size_t)s * H + k) * NR + r];
  cvec[t] = acc;
}

// ---------- helpers for main kernel ----------
__device__ __forceinline__ void stage64x256(u16* Wst, const u16* g, int tid) {
  // copy 64 rows x 256 bf16 (row stride 512 in global) into LDS rows of stride 264
#pragma unroll
  for (int i = 0; i < 4; i++) {
    int u = tid + i * 512;
    int n = u >> 5, kk = (u & 31) * 8;
    *(uint4*)&Wst[n * 264 + kk] = *(const uint4*)&g[n * 512 + kk];
  }
}

__device__ __forceinline__ void mfma_half(const u16* Wst, const bf16x8* afrag, int half,
                                          int lnm, int lnq, f32x4 acc[4]) {
#pragma unroll
  for (int ks = 0; ks < 8; ks++) {
    bf16x8 a = afrag[half * 8 + ks];
#pragma unroll
    for (int ct = 0; ct < 4; ct++) {
      bf16x8 b = *(const bf16x8*)&Wst[(ct * 16 + lnm) * 264 + ks * 32 + lnq * 8];
      acc[ct] = __builtin_amdgcn_mfma_f32_16x16x32_bf16(a, b, acc[ct], 0, 0, 0);
    }
  }
}

// ---------- main fused kernel: M=128 rows per block, 8 waves ----------
__global__ __launch_bounds__(512, 2) void moe_main(
    const float* __restrict__ enc, const u16* __restrict__ W1T,
    const u16* __restrict__ UcatT, const u16* __restrict__ W2T,
    const float* __restrict__ cvec, const float* __restrict__ b1g,
    const float* __restrict__ b2g, float* __restrict__ out) {
  __shared__ __align__(16) u16 Wst[64 * 264];    // 33792 B weight half-chunk
  __shared__ __align__(16) u16 h1c[128 * 72];    // 18432 B h1 chunk (pad 64->72)
  __shared__ float b1s[H];                       // 2048 B
  __shared__ float distS[NS][128];               // 4096 B
  __shared__ float alphS[NS][128];               // 4096 B
  __shared__ float cst[NS * NR];                 // 2048 B   (total 64512 B)

  const int tid = threadIdx.x;
  const int wave = tid >> 6, lane = tid & 63;
  const int lnm = lane & 15, lnq = lane >> 4;
  const int row0 = blockIdx.x * 128;
  const int myrow = row0 + wave * 16 + lnm;

  cst[tid] = cvec[tid];

  // load A fragments (raw encodings, bf16) into registers: 16 k-steps x 8 elems
  bf16x8 afrag[16];
  {
    const float* rp = enc + (size_t)myrow * H + lnq * 8;
#pragma unroll
    for (int ks = 0; ks < 16; ks++) {
      float4 x0 = *(const float4*)(rp + ks * 32);
      float4 x1 = *(const float4*)(rp + ks * 32 + 4);
      bf16x8 a;
      a[0] = (__bf16)x0.x; a[1] = (__bf16)x0.y; a[2] = (__bf16)x0.z; a[3] = (__bf16)x0.w;
      a[4] = (__bf16)x1.x; a[5] = (__bf16)x1.y; a[6] = (__bf16)x1.z; a[7] = (__bf16)x1.w;
      afrag[ks] = a;
    }
  }

  // ---------------- routing: dist[s][row] = ||enc@Us[s] - c[s]|| ----------------
#pragma unroll 1
  for (int s2 = 0; s2 < NS; s2++) {
    f32x4 acc[4] = {};
    const u16* ub = UcatT + (size_t)s2 * 64 * H;
    __syncthreads();
    stage64x256(Wst, ub, tid);
    __syncthreads();
    mfma_half(Wst, afrag, 0, lnm, lnq, acc);
    __syncthreads();
    stage64x256(Wst, ub + 256, tid);
    __syncthreads();
    mfma_half(Wst, afrag, 1, lnm, lnq, acc);

    float dsq[4] = {0.f, 0.f, 0.f, 0.f};
#pragma unroll
    for (int ct = 0; ct < 4; ct++) {
      float cv = cst[s2 * 64 + ct * 16 + lnm];
#pragma unroll
      for (int g = 0; g < 4; g++) { float d = acc[ct][g] - cv; dsq[g] += d * d; }
    }
#pragma unroll
    for (int m = 1; m < 16; m <<= 1) {
#pragma unroll
      for (int g = 0; g < 4; g++) dsq[g] += __shfl_xor(dsq[g], m, 16);
    }
    if (lnm == 0) {
#pragma unroll
      for (int g = 0; g < 4; g++) distS[s2][wave * 16 + lnq * 4 + g] = sqrtf(dsq[g]);
    }
  }
  __syncthreads();
  // softmax over sources (alpha = softmax(-dist))
  if (tid < 128) {
    float dmin = distS[0][tid];
#pragma unroll
    for (int s = 1; s < NS; s++) dmin = fminf(dmin, distS[s][tid]);
    float den = 0.f, e[NS];
#pragma unroll
    for (int s = 0; s < NS; s++) { e[s] = __expf(dmin - distS[s][tid]); den += e[s]; }
    float inv = 1.f / den;
#pragma unroll
    for (int s = 0; s < NS; s++) alphS[s][tid] = e[s] * inv;
  }
  // relu the A fragments in place (h0 = relu(enc), bf16-exact)
#pragma unroll
  for (int ks = 0; ks < 16; ks++) {
    union { bf16x8 v; u16 u[8]; } w; w.v = afrag[ks];
#pragma unroll
    for (int j = 0; j < 8; j++) if (w.u[j] & 0x8000) w.u[j] = 0;
    afrag[ks] = w.v;
  }
  __syncthreads();

  // ---------------- classifier: per-source MLP + weighted combine ----------------
  float fin[4] = {0.f, 0.f, 0.f, 0.f};
#pragma unroll 1
  for (int s = 0; s < NS; s++) {
    __syncthreads();
    b1s[tid] = b1g[s * H + tid];
    float b2v = (lnm < NT) ? b2g[s * NT + lnm] : 0.f;
    f32x4 oacc = {};
#pragma unroll 1
    for (int ch = 0; ch < 8; ch++) {
      f32x4 acc[4] = {};
      const u16* wb = W1T + ((size_t)s * H + ch * 64) * H;
      __syncthreads();
      stage64x256(Wst, wb, tid);
      __syncthreads();
      mfma_half(Wst, afrag, 0, lnm, lnq, acc);
      __syncthreads();
      stage64x256(Wst, wb + 256, tid);
      __syncthreads();
      mfma_half(Wst, afrag, 1, lnm, lnq, acc);
      // h1 = relu(acc + b1) -> LDS (bf16), each wave writes its own 16 rows
#pragma unroll
      for (int ct = 0; ct < 4; ct++) {
        int n = ch * 64 + ct * 16 + lnm;
        float bb = b1s[n];
#pragma unroll
        for (int g = 0; g < 4; g++) {
          float v = fmaxf(acc[ct][g] + bb, 0.f);
          h1c[(wave * 16 + lnq * 4 + g) * 72 + ct * 16 + lnm] = f2bf(v);
        }
      }
      __syncthreads();
      // second GEMM partial: oacc += h1chunk @ W2T[s][:, chunk]
#pragma unroll
      for (int st = 0; st < 2; st++) {
        bf16x8 a2 = *(const bf16x8*)&h1c[(wave * 16 + lnm) * 72 + st * 32 + lnq * 8];
        bf16x8 bw = *(const bf16x8*)&W2T[((size_t)s * 16 + lnm) * H + ch * 64 + st * 32 + lnq * 8];
        oacc = __builtin_amdgcn_mfma_f32_16x16x32_bf16(a2, bw, oacc, 0, 0, 0);
      }
    }
    // sigmoid + alpha-weighted accumulate
#pragma unroll
    for (int g = 0; g < 4; g++) {
      float pre = oacc[g] + b2v;
      float sig = 1.f / (1.f + __expf(-pre));
      fin[g] += alphS[s][wave * 16 + lnq * 4 + g] * sig;
    }
  }
  // write output rows (each wave owns its 16 rows; cols t = lnm < 12)
  if (lnm < NT) {
#pragma unroll
    for (int g = 0; g < 4; g++) {
      int rg = row0 + wave * 16 + lnq * 4 + g;
      out[(size_t)rg * NT + lnm] = fin[g];
    }
  }
}

extern "C" void kernel_launch(void* const* d_in, const int* in_sizes, int n_in,
                              void* d_out, int out_size, void* d_ws, size_t ws_size,
                              hipStream_t stream) {
  const float* enc = (const float*)d_in[0];
  const float* mu  = (const float*)d_in[1];
  const float* Us  = (const float*)d_in[2];
  const float* W1  = (const float*)d_in[3];
  const float* b1  = (const float*)d_in[4];
  const float* W2  = (const float*)d_in[5];
  const float* b2  = (const float*)d_in[6];
  float* out = (float*)d_out;
  char* ws = (char*)d_ws;
  u16* W1T   = (u16*)(ws + WS_W1T);
  u16* UcatT = (u16*)(ws + WS_UCT);
  u16* W2T   = (u16*)(ws + WS_W2T);
  float* cvec = (float*)(ws + WS_CVEC);

  dim3 tb(32, 8, 1);
  transpose_cast<<<dim3(16, 16, 8), tb, 0, stream>>>(W1, W1T, 512, 512, 512);
  transpose_cast<<<dim3(16, 2, 8),  tb, 0, stream>>>(Us, UcatT, 512, 64, 64);
  transpose_cast<<<dim3(16, 1, 8),  tb, 0, stream>>>(W2, W2T, 512, 12, 16);
  compute_c<<<1, 512, 0, stream>>>(mu, Us, cvec);
  moe_main<<<256, 512, 0, stream>>>(enc, W1T, UcatT, W2T, cvec, b1, b2, out);
}